// Round 1
// baseline (760.373 us; speedup 1.0000x reference)
//
#include <hip/hip_runtime.h>
#include <hip/hip_bf16.h>
#include <math.h>

// Problem constants
#define BB   256
#define NN   180
#define CC   768
#define RR   192
#define MROWS (BB*NN)      // 46080 flat rows
#define KPAD 192           // node-dim padded to 192 for GEMM3 K

typedef __attribute__((ext_vector_type(8))) __bf16 bf16x8;
typedef __attribute__((ext_vector_type(4))) __bf16 bf16x4;
typedef __attribute__((ext_vector_type(4))) float  floatx4;

#define LDK 40   // LDS row stride (32 k + 8 pad) keeps 16B alignment of frags

// ---------------------------------------------------------------------------
// Generic 64x64-tile bf16 MFMA GEMM, B given transposed (Bt[n][k]).
// MODE 0: out bf16, val=(acc+bias[n])*scale[n]            (Q/K projection)
// MODE 1: out bf16, raw                                    (scores)
// MODE 2: out bf16, raw                                    (z = A@x)
// MODE 3: out f32,  val=relu(acc+bias[n]) + addx[m*ldc+n]  (z@Wg + residual)
// ---------------------------------------------------------------------------
template<int MODE>
__global__ __launch_bounds__(256) void gemm_bt(
    const __bf16* __restrict__ A,  int lda, long sAb,
    const __bf16* __restrict__ Bt, int ldb, long sBb,
    void* __restrict__ Cout, int ldc, long sCb,
    int M, int N, int K,
    const float* __restrict__ bias,
    const float* __restrict__ scale,
    const float* __restrict__ addx)
{
    const int z = blockIdx.z;
    const __bf16* Ab = A  + (long)z * sAb;
    const __bf16* Bb = Bt + (long)z * sBb;
    const int m0 = blockIdx.y * 64;
    const int n0 = blockIdx.x * 64;
    const int t  = threadIdx.x;
    const int w  = t >> 6;        // wave id 0..3 -> 16-row strip
    const int l  = t & 63;
    const int lr = l & 15;        // lane row/col within 16
    const int q  = l >> 4;        // quad 0..3

    __shared__ __align__(16) __bf16 lds_a[64 * LDK];
    __shared__ __align__(16) __bf16 lds_b[64 * LDK];

    floatx4 acc[4] = {};

    // staging map: thread -> (row 0..63, k-chunk of 8)
    const int srow = t >> 2;
    const int skc  = (t & 3) * 8;

    for (int k0 = 0; k0 < K; k0 += 32) {
        bf16x8 av = {};
        int am = m0 + srow;
        if (am < M) av = *reinterpret_cast<const bf16x8*>(Ab + (long)am * lda + k0 + skc);
        *reinterpret_cast<bf16x8*>(&lds_a[srow * LDK + skc]) = av;

        bf16x8 bv = {};
        int bn = n0 + srow;
        if (bn < N) bv = *reinterpret_cast<const bf16x8*>(Bb + (long)bn * ldb + k0 + skc);
        *reinterpret_cast<bf16x8*>(&lds_b[srow * LDK + skc]) = bv;

        __syncthreads();

        bf16x8 af = *reinterpret_cast<const bf16x8*>(&lds_a[(w * 16 + lr) * LDK + q * 8]);
#pragma unroll
        for (int s = 0; s < 4; ++s) {
            bf16x8 bfv = *reinterpret_cast<const bf16x8*>(&lds_b[(s * 16 + lr) * LDK + q * 8]);
            acc[s] = __builtin_amdgcn_mfma_f32_16x16x32_bf16(af, bfv, acc[s], 0, 0, 0);
        }
        __syncthreads();
    }

    // epilogue: D row=(q*4+r), col=lr within each 16x16 subtile
#pragma unroll
    for (int s = 0; s < 4; ++s) {
#pragma unroll
        for (int r = 0; r < 4; ++r) {
            int m = m0 + w * 16 + q * 4 + r;
            int n = n0 + s * 16 + lr;
            if (m < M && n < N) {
                float v = acc[s][r];
                if (MODE == 0) {
                    v = (v + bias[n]) * scale[n];
                    ((__bf16*)Cout)[(long)z * sCb + (long)m * ldc + n] = (__bf16)v;
                } else if (MODE == 1 || MODE == 2) {
                    ((__bf16*)Cout)[(long)z * sCb + (long)m * ldc + n] = (__bf16)v;
                } else { // MODE 3
                    v = v + bias[n];
                    v = v > 0.f ? v : 0.f;
                    v += addx[(long)m * ldc + n];
                    ((float*)Cout)[(long)m * ldc + n] = v;
                }
            }
        }
    }
}

// ---------------------------------------------------------------------------
// x (f32) -> xb (bf16), vectorized
// ---------------------------------------------------------------------------
__global__ __launch_bounds__(256) void convert_x(const float4* __restrict__ x4,
                                                 __bf16* __restrict__ xb, int n4)
{
    int i = blockIdx.x * 256 + threadIdx.x;
    int stride = gridDim.x * 256;
    for (; i < n4; i += stride) {
        float4 v = x4[i];
        bf16x4 o;
        o[0] = (__bf16)v.x; o[1] = (__bf16)v.y; o[2] = (__bf16)v.z; o[3] = (__bf16)v.w;
        *reinterpret_cast<bf16x4*>(xb + 4 * (long)i) = o;
    }
}

// ---------------------------------------------------------------------------
// Weights: WqkT[384][768] = [Wq|Wk]^T (bf16), WgT[768][768] = Wg^T (bf16),
// plus combined bias[384] and per-column scale[384] (1/sqrt(R) on Q cols).
// ---------------------------------------------------------------------------
__global__ __launch_bounds__(256) void prep_weights(
    const float* __restrict__ Wq, const float* __restrict__ bq,
    const float* __restrict__ Wk, const float* __restrict__ bk,
    const float* __restrict__ Wg,
    __bf16* __restrict__ WqkT, __bf16* __restrict__ WgT,
    float* __restrict__ biasqk, float* __restrict__ scaleqk)
{
    int blk = blockIdx.x, t = threadIdx.x;
    if (blk < 384) {
        int n = blk;
        const float* W = (n < RR) ? Wq : Wk;
        int nn = (n < RR) ? n : n - RR;
        for (int k = t; k < CC; k += 256)
            WqkT[(long)n * CC + k] = (__bf16)W[(long)k * RR + nn];
        if (blk == 0) {
            for (int i = t; i < 384; i += 256) {
                biasqk[i]  = (i < RR) ? bq[i] : bk[i - RR];
                scaleqk[i] = (i < RR) ? rsqrtf((float)RR) : 1.0f;
            }
        }
    } else {
        int n = blk - 384;
        for (int k = t; k < CC; k += 256)
            WgT[(long)n * CC + k] = (__bf16)Wg[(long)k * CC + n];
    }
}

// ---------------------------------------------------------------------------
// xbT[b][c][m] (m padded to 192, zeros) from xb[b][m][c]; LDS tile transpose.
// grid: (12 c-chunks) x 256 b  -> blockIdx.x = b*12 + cchunk
// ---------------------------------------------------------------------------
__global__ __launch_bounds__(256) void transpose_x(const __bf16* __restrict__ xb,
                                                   __bf16* __restrict__ xbT)
{
    const int c0 = (blockIdx.x % 12) * 64;
    const int b  = blockIdx.x / 12;
    __shared__ __bf16 lds[64 * 194];   // [c][m], stride 194 (odd-ish -> conflict-free)
    const int t = threadIdx.x;

    for (int i = 0; i < 45; ++i) {               // 180*64/256
        int idx = i * 256 + t;
        int m = idx >> 6, c = idx & 63;
        lds[c * 194 + m] = xb[((long)(b * NN + m)) * CC + c0 + c];
    }
    __syncthreads();
    for (int j = 0; j < 48; ++j) {               // 64*192/256
        int idx = j * 256 + t;
        int c = idx / KPAD, m = idx % KPAD;
        __bf16 v = (m < NN) ? lds[c * 194 + m] : (__bf16)0.0f;
        xbT[((long)(b * CC + c0 + c)) * KPAD + m] = v;
    }
}

// ---------------------------------------------------------------------------
// Row softmax of S (bf16, [B][180][180]) + combine with alpha/A_phys,
// write A_comb bf16 [B][180][192] (K-padded with zeros). One wave per row.
// ---------------------------------------------------------------------------
__global__ __launch_bounds__(256) void softmax_combine(
    const __bf16* __restrict__ S, const float* __restrict__ A_phys,
    const float* __restrict__ alpha, __bf16* __restrict__ Acomb)
{
    const int w = threadIdx.x >> 6, l = threadIdx.x & 63;
    const long row = (long)blockIdx.x * 4 + w;          // 0..46079
    const int b = (int)(row / NN), n = (int)(row % NN);
    const __bf16* Srow = S + ((long)b * NN + n) * NN;

    float v[3];
#pragma unroll
    for (int i = 0; i < 3; ++i) {
        int m = l + 64 * i;
        v[i] = (m < NN) ? (float)Srow[m] : -1e30f;
    }
    float mx = fmaxf(fmaxf(v[0], v[1]), v[2]);
    for (int off = 32; off; off >>= 1) mx = fmaxf(mx, __shfl_xor(mx, off, 64));

    float e[3], sum = 0.f;
#pragma unroll
    for (int i = 0; i < 3; ++i) {
        int m = l + 64 * i;
        e[i] = (m < NN) ? expf(v[i] - mx) : 0.f;
        sum += e[i];
    }
    for (int off = 32; off; off >>= 1) sum += __shfl_xor(sum, off, 64);

    const float a   = 1.f / (1.f + expf(-alpha[0]));
    const float inv = (1.f - a) / sum;
    __bf16* Orow = Acomb + ((long)b * NN + n) * KPAD;
#pragma unroll
    for (int i = 0; i < 3; ++i) {
        int m = l + 64 * i;
        if (m < KPAD) {
            float o = (m < NN) ? (a * A_phys[n * NN + m] + e[i] * inv) : 0.f;
            Orow[m] = (__bf16)o;
        }
    }
}

// ---------------------------------------------------------------------------
// In-place LayerNorm over channel dim; one block per row of 768.
// ---------------------------------------------------------------------------
__global__ __launch_bounds__(256) void ln_kernel(float* __restrict__ out,
                                                 const float* __restrict__ gamma,
                                                 const float* __restrict__ beta)
{
    float* p = out + (long)blockIdx.x * CC;
    const int t = threadIdx.x, w = t >> 6, l = t & 63;
    float h[3], s = 0.f, s2 = 0.f;
#pragma unroll
    for (int i = 0; i < 3; ++i) {
        h[i] = p[t + 256 * i];
        s += h[i]; s2 += h[i] * h[i];
    }
    for (int off = 32; off; off >>= 1) { s += __shfl_xor(s, off, 64); s2 += __shfl_xor(s2, off, 64); }
    __shared__ float ps[4], ps2[4];
    if (l == 0) { ps[w] = s; ps2[w] = s2; }
    __syncthreads();
    s  = ps[0] + ps[1] + ps[2] + ps[3];
    s2 = ps2[0] + ps2[1] + ps2[2] + ps2[3];
    const float mu  = s * (1.f / CC);
    const float var = s2 * (1.f / CC) - mu * mu;
    const float rs  = rsqrtf(var + 1e-5f);
#pragma unroll
    for (int i = 0; i < 3; ++i) {
        int c = t + 256 * i;
        p[c] = (h[i] - mu) * rs * gamma[c] + beta[c];
    }
}

// ---------------------------------------------------------------------------
extern "C" void kernel_launch(void* const* d_in, const int* in_sizes, int n_in,
                              void* d_out, int out_size, void* d_ws, size_t ws_size,
                              hipStream_t stream)
{
    const float* x      = (const float*)d_in[0];
    const float* Wq     = (const float*)d_in[1];
    const float* bq     = (const float*)d_in[2];
    const float* Wk     = (const float*)d_in[3];
    const float* bk     = (const float*)d_in[4];
    const float* Wg     = (const float*)d_in[5];
    const float* bg     = (const float*)d_in[6];
    const float* gamma  = (const float*)d_in[7];
    const float* beta   = (const float*)d_in[8];
    const float* alpha  = (const float*)d_in[9];
    const float* A_phys = (const float*)d_in[10];

    // ---- workspace carve (bytes). Lifetime aliases: z over xb, Acomb over QK.
    char* w = (char*)d_ws;
    __bf16* xb    = (__bf16*)(w + 0);                       // 70,778,880  (also z)
    __bf16* zbuf  = xb;
    __bf16* xbT   = (__bf16*)(w + 70778880);                // 75,497,472
    __bf16* QK    = (__bf16*)(w + 146276352);               // 35,389,440  (also Acomb)
    __bf16* Acomb = QK;
    __bf16* S     = (__bf16*)(w + 181665792);               // 16,588,800
    __bf16* WqkT  = (__bf16*)(w + 198254592);               //    589,824
    __bf16* WgT   = (__bf16*)(w + 198844416);               //  1,179,648
    float*  biasqk  = (float*)(w + 200024064);              //      1,536
    float*  scaleqk = (float*)(w + 200025600);              //      1,536
    // total 200,027,136 bytes

    // 1) conversions / transposes
    convert_x<<<4096, 256, 0, stream>>>((const float4*)x, xb, MROWS * CC / 4);
    prep_weights<<<384 + CC, 256, 0, stream>>>(Wq, bq, Wk, bk, Wg, WqkT, WgT, biasqk, scaleqk);
    transpose_x<<<BB * 12, 256, 0, stream>>>(xb, xbT);

    // 2) GEMM1: [46080,768] @ WqkT^T -> QK [46080,384] bf16 (Q scaled by 1/sqrt(R))
    gemm_bt<0><<<dim3(384 / 64, MROWS / 64, 1), 256, 0, stream>>>(
        xb, CC, 0L, WqkT, CC, 0L, QK, 384, 0L,
        MROWS, 384, CC, biasqk, scaleqk, nullptr);

    // 3) GEMM2 (batched): S[b] = Q[b] (180x192) @ K[b]^T -> [180,180] bf16
    gemm_bt<1><<<dim3(3, 3, BB), 256, 0, stream>>>(
        QK, 384, (long)NN * 384, QK + RR, 384, (long)NN * 384,
        S, NN, (long)NN * NN,
        NN, NN, RR, nullptr, nullptr, nullptr);

    // 4) softmax + alpha combine -> Acomb [B][180][192] bf16 (overwrites QK region)
    softmax_combine<<<MROWS / 4, 256, 0, stream>>>(S, A_phys, alpha, Acomb);

    // 5) GEMM3 (batched): z[b] = Acomb[b] (180x192) @ xbT[b]^T (192x768) -> bf16
    gemm_bt<2><<<dim3(CC / 64, 3, BB), 256, 0, stream>>>(
        Acomb, KPAD, (long)NN * KPAD, xbT, KPAD, (long)CC * KPAD,
        zbuf, CC, (long)NN * CC,
        NN, CC, KPAD, nullptr, nullptr, nullptr);

    // 6) GEMM4: h = x + relu(z @ Wg + bg) -> d_out f32 [46080,768]
    gemm_bt<3><<<dim3(CC / 64, MROWS / 64, 1), 256, 0, stream>>>(
        zbuf, CC, 0L, WgT, CC, 0L, d_out, CC, 0L,
        MROWS, CC, CC, bg, nullptr, x);

    // 7) in-place LayerNorm
    ln_kernel<<<MROWS, 256, 0, stream>>>((float*)d_out, gamma, beta);
}

// Round 2
// 701.556 us; speedup vs baseline: 1.0838x; 1.0838x over previous
//
#include <hip/hip_runtime.h>
#include <hip/hip_bf16.h>
#include <math.h>
#include <stdint.h>

// Problem constants
#define BB   256
#define NN   180
#define CC   768
#define RR   192
#define MROWS (BB*NN)      // 46080 flat rows
#define KPAD 192           // node-dim padded to 192 for GEMM3 K

typedef __attribute__((ext_vector_type(8))) __bf16 bf16x8;
typedef __attribute__((ext_vector_type(4))) __bf16 bf16x4;
typedef __attribute__((ext_vector_type(4))) float  floatx4;

// async global->LDS, 16 B per lane. LDS dest is wave-uniform base + lane*16.
__device__ __forceinline__ void gload_lds16(const __bf16* g, __bf16* lds)
{
    __builtin_amdgcn_global_load_lds(
        (const __attribute__((address_space(1))) void*)(uintptr_t)(const void*)g,
        (__attribute__((address_space(3))) void*)(uintptr_t)(void*)lds,
        16, 0, 0);
}

// ---------------------------------------------------------------------------
// 128x128-tile bf16 MFMA GEMM (m97 structure), B transposed (Bt[n][k]).
// 4 waves, each computes a 64x64 patch (4x4 grid of 16x16x32 MFMA).
// Staging: global_load_lds 16B/lane into unpadded [row][k] LDS (32-elem rows).
// MODE 0: out bf16, val=(acc+bias[n])*scale[n]            (Q/K projection)
// MODE 1: out bf16, raw                                    (scores / z)
// MODE 3: out f32,  val=relu(acc+bias[n]) + addx[m*ldc+n]  (z@Wg + residual)
// M,N may be non-multiples of 128: staging rows clamp, epilogue guards.
// K must be a multiple of 32; all staged K-addresses must be valid.
// ---------------------------------------------------------------------------
template<int MODE>
__global__ __launch_bounds__(256) void gemm128(
    const __bf16* __restrict__ A,  int lda, long sAb,
    const __bf16* __restrict__ Bt, int ldb, long sBb,
    void* __restrict__ Cout, int ldc, long sCb,
    int M, int N, int K,
    const float* __restrict__ bias,
    const float* __restrict__ scale,
    const float* __restrict__ addx)
{
    const int z = blockIdx.z;
    const __bf16* Ab = A  + (long)z * sAb;
    const __bf16* Bb = Bt + (long)z * sBb;
    const int m0 = blockIdx.y * 128;
    const int n0 = blockIdx.x * 128;
    const int t  = threadIdx.x;
    const int w  = t >> 6;
    const int l  = t & 63;
    const int lr = l & 15;
    const int q  = l >> 4;

    __shared__ __align__(16) __bf16 sa[128 * 32];   // 8 KB, unpadded (lds-dma layout)
    __shared__ __align__(16) __bf16 sb[128 * 32];   // 8 KB

    floatx4 acc[4][4] = {};

    const int wm = (w & 1) * 64;     // wave's m-offset within tile
    const int wn = (w >> 1) * 64;    // wave's n-offset within tile

    // staging lane map: chunk = 16 rows x 32 k (1024 B); lane l -> row l/4, kelem (l&3)*8
    const int srow = l >> 2;
    const int skc  = (l & 3) * 8;

    int arow0 = m0 + w * 16 + srow;        if (arow0 > M - 1) arow0 = M - 1;
    int arow1 = m0 + (w + 4) * 16 + srow;  if (arow1 > M - 1) arow1 = M - 1;
    int brow0 = n0 + w * 16 + srow;        if (brow0 > N - 1) brow0 = N - 1;
    int brow1 = n0 + (w + 4) * 16 + srow;  if (brow1 > N - 1) brow1 = N - 1;

    const __bf16* agp0 = Ab + (long)arow0 * lda + skc;
    const __bf16* agp1 = Ab + (long)arow1 * lda + skc;
    const __bf16* bgp0 = Bb + (long)brow0 * ldb + skc;
    const __bf16* bgp1 = Bb + (long)brow1 * ldb + skc;

    __bf16* sa0 = sa + (size_t)w * 512;          // wave-uniform chunk bases
    __bf16* sa1 = sa + (size_t)(w + 4) * 512;
    __bf16* sb0 = sb + (size_t)w * 512;
    __bf16* sb1 = sb + (size_t)(w + 4) * 512;

    for (int k0 = 0; k0 < K; k0 += 32) {
        gload_lds16(agp0 + k0, sa0);
        gload_lds16(agp1 + k0, sa1);
        gload_lds16(bgp0 + k0, sb0);
        gload_lds16(bgp1 + k0, sb1);
        __syncthreads();   // drains vmcnt (async LDS-DMA) per barrier semantics

        bf16x8 af[4], bfv[4];
#pragma unroll
        for (int i = 0; i < 4; ++i)
            af[i] = *reinterpret_cast<const bf16x8*>(&sa[(wm + i * 16 + lr) * 32 + q * 8]);
#pragma unroll
        for (int j = 0; j < 4; ++j)
            bfv[j] = *reinterpret_cast<const bf16x8*>(&sb[(wn + j * 16 + lr) * 32 + q * 8]);
#pragma unroll
        for (int i = 0; i < 4; ++i)
#pragma unroll
            for (int j = 0; j < 4; ++j)
                acc[i][j] = __builtin_amdgcn_mfma_f32_16x16x32_bf16(af[i], bfv[j], acc[i][j], 0, 0, 0);
        __syncthreads();
    }

    // epilogue: D subtile (i,j): row = q*4+r, col = lr
#pragma unroll
    for (int i = 0; i < 4; ++i) {
        const int mbase = m0 + wm + i * 16 + q * 4;
#pragma unroll
        for (int j = 0; j < 4; ++j) {
            const int n = n0 + wn + j * 16 + lr;
#pragma unroll
            for (int r = 0; r < 4; ++r) {
                const int m = mbase + r;
                if (m < M && n < N) {
                    float v = acc[i][j][r];
                    if (MODE == 0) {
                        v = (v + bias[n]) * scale[n];
                        ((__bf16*)Cout)[(long)z * sCb + (long)m * ldc + n] = (__bf16)v;
                    } else if (MODE == 1) {
                        ((__bf16*)Cout)[(long)z * sCb + (long)m * ldc + n] = (__bf16)v;
                    } else { // MODE 3
                        v = v + bias[n];
                        v = v > 0.f ? v : 0.f;
                        v += addx[(long)m * ldc + n];
                        ((float*)Cout)[(long)m * ldc + n] = v;
                    }
                }
            }
        }
    }
}

// ---------------------------------------------------------------------------
// x (f32) -> xb (bf16), vectorized
// ---------------------------------------------------------------------------
__global__ __launch_bounds__(256) void convert_x(const float4* __restrict__ x4,
                                                 __bf16* __restrict__ xb, int n4)
{
    int i = blockIdx.x * 256 + threadIdx.x;
    int stride = gridDim.x * 256;
    for (; i < n4; i += stride) {
        float4 v = x4[i];
        bf16x4 o;
        o[0] = (__bf16)v.x; o[1] = (__bf16)v.y; o[2] = (__bf16)v.z; o[3] = (__bf16)v.w;
        *reinterpret_cast<bf16x4*>(xb + 4 * (long)i) = o;
    }
}

// ---------------------------------------------------------------------------
// Weights: WqkT[384][768] = [Wq|Wk]^T (bf16), WgT[768][768] = Wg^T (bf16),
// plus combined bias[384] and per-column scale[384] (1/sqrt(R) on Q cols).
// ---------------------------------------------------------------------------
__global__ __launch_bounds__(256) void prep_weights(
    const float* __restrict__ Wq, const float* __restrict__ bq,
    const float* __restrict__ Wk, const float* __restrict__ bk,
    const float* __restrict__ Wg,
    __bf16* __restrict__ WqkT, __bf16* __restrict__ WgT,
    float* __restrict__ biasqk, float* __restrict__ scaleqk)
{
    int blk = blockIdx.x, t = threadIdx.x;
    if (blk < 384) {
        int n = blk;
        const float* W = (n < RR) ? Wq : Wk;
        int nn = (n < RR) ? n : n - RR;
        for (int k = t; k < CC; k += 256)
            WqkT[(long)n * CC + k] = (__bf16)W[(long)k * RR + nn];
        if (blk == 0) {
            for (int i = t; i < 384; i += 256) {
                biasqk[i]  = (i < RR) ? bq[i] : bk[i - RR];
                scaleqk[i] = (i < RR) ? rsqrtf((float)RR) : 1.0f;
            }
        }
    } else {
        int n = blk - 384;
        for (int k = t; k < CC; k += 256)
            WgT[(long)n * CC + k] = (__bf16)Wg[(long)k * CC + n];
    }
}

// ---------------------------------------------------------------------------
// xbT[b][c][m] (m padded to 192, zeros) from xb[b][m][c]; LDS tile transpose.
// ---------------------------------------------------------------------------
__global__ __launch_bounds__(256) void transpose_x(const __bf16* __restrict__ xb,
                                                   __bf16* __restrict__ xbT)
{
    const int c0 = (blockIdx.x % 12) * 64;
    const int b  = blockIdx.x / 12;
    __shared__ __bf16 lds[64 * 194];
    const int t = threadIdx.x;

    for (int i = 0; i < 45; ++i) {
        int idx = i * 256 + t;
        int m = idx >> 6, c = idx & 63;
        lds[c * 194 + m] = xb[((long)(b * NN + m)) * CC + c0 + c];
    }
    __syncthreads();
    for (int j = 0; j < 48; ++j) {
        int idx = j * 256 + t;
        int c = idx / KPAD, m = idx % KPAD;
        __bf16 v = (m < NN) ? lds[c * 194 + m] : (__bf16)0.0f;
        xbT[((long)(b * CC + c0 + c)) * KPAD + m] = v;
    }
}

// ---------------------------------------------------------------------------
// Row softmax of S (bf16, [B][180][180]) + combine with alpha/A_phys,
// write A_comb bf16 [B][180][192] (K-padded with zeros). One wave per row.
// ---------------------------------------------------------------------------
__global__ __launch_bounds__(256) void softmax_combine(
    const __bf16* __restrict__ S, const float* __restrict__ A_phys,
    const float* __restrict__ alpha, __bf16* __restrict__ Acomb)
{
    const int w = threadIdx.x >> 6, l = threadIdx.x & 63;
    const long row = (long)blockIdx.x * 4 + w;
    const int b = (int)(row / NN), n = (int)(row % NN);
    const __bf16* Srow = S + ((long)b * NN + n) * NN;

    float v[3];
#pragma unroll
    for (int i = 0; i < 3; ++i) {
        int m = l + 64 * i;
        v[i] = (m < NN) ? (float)Srow[m] : -1e30f;
    }
    float mx = fmaxf(fmaxf(v[0], v[1]), v[2]);
    for (int off = 32; off; off >>= 1) mx = fmaxf(mx, __shfl_xor(mx, off, 64));

    float e[3], sum = 0.f;
#pragma unroll
    for (int i = 0; i < 3; ++i) {
        int m = l + 64 * i;
        e[i] = (m < NN) ? expf(v[i] - mx) : 0.f;
        sum += e[i];
    }
    for (int off = 32; off; off >>= 1) sum += __shfl_xor(sum, off, 64);

    const float a   = 1.f / (1.f + expf(-alpha[0]));
    const float inv = (1.f - a) / sum;
    __bf16* Orow = Acomb + ((long)b * NN + n) * KPAD;
#pragma unroll
    for (int i = 0; i < 3; ++i) {
        int m = l + 64 * i;
        if (m < KPAD) {
            float o = (m < NN) ? (a * A_phys[n * NN + m] + e[i] * inv) : 0.f;
            Orow[m] = (__bf16)o;
        }
    }
}

// ---------------------------------------------------------------------------
// In-place LayerNorm over channel dim; one block per row of 768.
// ---------------------------------------------------------------------------
__global__ __launch_bounds__(256) void ln_kernel(float* __restrict__ out,
                                                 const float* __restrict__ gamma,
                                                 const float* __restrict__ beta)
{
    float* p = out + (long)blockIdx.x * CC;
    const int t = threadIdx.x, w = t >> 6, l = t & 63;
    float h[3], s = 0.f, s2 = 0.f;
#pragma unroll
    for (int i = 0; i < 3; ++i) {
        h[i] = p[t + 256 * i];
        s += h[i]; s2 += h[i] * h[i];
    }
    for (int off = 32; off; off >>= 1) { s += __shfl_xor(s, off, 64); s2 += __shfl_xor(s2, off, 64); }
    __shared__ float ps[4], ps2[4];
    if (l == 0) { ps[w] = s; ps2[w] = s2; }
    __syncthreads();
    s  = ps[0] + ps[1] + ps[2] + ps[3];
    s2 = ps2[0] + ps2[1] + ps2[2] + ps2[3];
    const float mu  = s * (1.f / CC);
    const float var = s2 * (1.f / CC) - mu * mu;
    const float rs  = rsqrtf(var + 1e-5f);
#pragma unroll
    for (int i = 0; i < 3; ++i) {
        int c = t + 256 * i;
        p[c] = (h[i] - mu) * rs * gamma[c] + beta[c];
    }
}

// ---------------------------------------------------------------------------
extern "C" void kernel_launch(void* const* d_in, const int* in_sizes, int n_in,
                              void* d_out, int out_size, void* d_ws, size_t ws_size,
                              hipStream_t stream)
{
    const float* x      = (const float*)d_in[0];
    const float* Wq     = (const float*)d_in[1];
    const float* bq     = (const float*)d_in[2];
    const float* Wk     = (const float*)d_in[3];
    const float* bk     = (const float*)d_in[4];
    const float* Wg     = (const float*)d_in[5];
    const float* bg     = (const float*)d_in[6];
    const float* gamma  = (const float*)d_in[7];
    const float* beta   = (const float*)d_in[8];
    const float* alpha  = (const float*)d_in[9];
    const float* A_phys = (const float*)d_in[10];

    // ---- workspace carve (bytes). Lifetime aliases: z over xb, Acomb over QK.
    char* w = (char*)d_ws;
    __bf16* xb    = (__bf16*)(w + 0);                       // 70,778,880  (also z)
    __bf16* zbuf  = xb;
    __bf16* xbT   = (__bf16*)(w + 70778880);                // 75,497,472
    __bf16* QK    = (__bf16*)(w + 146276352);               // 35,389,440  (also Acomb)
    __bf16* Acomb = QK;
    __bf16* S     = (__bf16*)(w + 181665792);               // 16,588,800
    __bf16* WqkT  = (__bf16*)(w + 198254592);               //    589,824
    __bf16* WgT   = (__bf16*)(w + 198844416);               //  1,179,648
    float*  biasqk  = (float*)(w + 200024064);              //      1,536
    float*  scaleqk = (float*)(w + 200025600);              //      1,536

    // 1) conversions / transposes
    convert_x<<<4096, 256, 0, stream>>>((const float4*)x, xb, MROWS * CC / 4);
    prep_weights<<<384 + CC, 256, 0, stream>>>(Wq, bq, Wk, bk, Wg, WqkT, WgT, biasqk, scaleqk);
    transpose_x<<<BB * 12, 256, 0, stream>>>(xb, xbT);

    // 2) GEMM1: [46080,768] @ WqkT^T -> QK [46080,384] bf16 (Q scaled by 1/sqrt(R))
    gemm128<0><<<dim3(384 / 128, MROWS / 128, 1), 256, 0, stream>>>(
        xb, CC, 0L, WqkT, CC, 0L, QK, 384, 0L,
        MROWS, 384, CC, biasqk, scaleqk, nullptr);

    // 3) GEMM2 (batched): S[b] = Q[b] (180x192) @ K[b]^T -> [180,180] bf16
    gemm128<1><<<dim3(2, 2, BB), 256, 0, stream>>>(
        QK, 384, (long)NN * 384, QK + RR, 384, (long)NN * 384,
        S, NN, (long)NN * NN,
        NN, NN, RR, nullptr, nullptr, nullptr);

    // 4) softmax + alpha combine -> Acomb [B][180][192] bf16 (overwrites QK region)
    softmax_combine<<<MROWS / 4, 256, 0, stream>>>(S, A_phys, alpha, Acomb);

    // 5) GEMM3 (batched): z[b] = Acomb[b] (180x192) @ xbT[b]^T (192x768) -> bf16
    gemm128<1><<<dim3(CC / 128, 2, BB), 256, 0, stream>>>(
        Acomb, KPAD, (long)NN * KPAD, xbT, KPAD, (long)CC * KPAD,
        zbuf, CC, (long)NN * CC,
        NN, CC, KPAD, nullptr, nullptr, nullptr);

    // 6) GEMM4: h = x + relu(z @ Wg + bg) -> d_out f32 [46080,768]
    gemm128<3><<<dim3(CC / 128, MROWS / 128, 1), 256, 0, stream>>>(
        zbuf, CC, 0L, WgT, CC, 0L, d_out, CC, 0L,
        MROWS, CC, CC, bg, nullptr, x);

    // 7) in-place LayerNorm
    ln_kernel<<<MROWS, 256, 0, stream>>>((float*)d_out, gamma, beta);
}

// Round 3
// 684.271 us; speedup vs baseline: 1.1112x; 1.0253x over previous
//
#include <hip/hip_runtime.h>
#include <hip/hip_bf16.h>
#include <math.h>
#include <stdint.h>

// Problem constants
#define BB   256
#define NN   180
#define CC   768
#define RR   192
#define MROWS (BB*NN)      // 46080 flat rows
#define KPAD 192           // node-dim padded to 192 for GEMM3 K

typedef __attribute__((ext_vector_type(8))) __bf16 bf16x8;
typedef __attribute__((ext_vector_type(4))) __bf16 bf16x4;
typedef __attribute__((ext_vector_type(4))) float  floatx4;

// async global->LDS, 16 B per lane. LDS dest is wave-uniform base + lane*16.
__device__ __forceinline__ void gload_lds16(const __bf16* g, __bf16* lds)
{
    __builtin_amdgcn_global_load_lds(
        (const __attribute__((address_space(1))) void*)(uintptr_t)(const void*)g,
        (__attribute__((address_space(3))) void*)(uintptr_t)(void*)lds,
        16, 0, 0);
}

// ---------------------------------------------------------------------------
// 128x128-tile bf16 MFMA GEMM, B transposed (Bt[n][k]).
// 4 waves, each computes a 64x64 patch (4x4 grid of 16x16x32 MFMA).
// K-loop is double-buffered: LDS-DMA for chunk k+1 is issued BEFORE the MFMA
// work on chunk k, so the barrier's vmcnt(0) drain overlaps with compute.
// Requires K % 64 == 0 (true for 768 and 192).
// MODE 0: out bf16, val=(acc+bias[n])*scale[n]            (Q/K projection)
// MODE 1: out bf16, raw                                    (scores / z)
// MODE 3: out f32,  val=relu(acc+bias[n]) + addx[m*ldc+n]  (z@Wg + residual)
// ---------------------------------------------------------------------------
template<int MODE>
__global__ __launch_bounds__(256) void gemm128(
    const __bf16* __restrict__ A,  int lda, long sAb,
    const __bf16* __restrict__ Bt, int ldb, long sBb,
    void* __restrict__ Cout, int ldc, long sCb,
    int M, int N, int K,
    const float* __restrict__ bias,
    const float* __restrict__ scale,
    const float* __restrict__ addx)
{
    const int z = blockIdx.z;
    const __bf16* Ab = A  + (long)z * sAb;
    const __bf16* Bb = Bt + (long)z * sBb;
    const int m0 = blockIdx.y * 128;
    const int n0 = blockIdx.x * 128;
    const int t  = threadIdx.x;
    const int w  = t >> 6;
    const int l  = t & 63;
    const int lr = l & 15;
    const int q  = l >> 4;

    __shared__ __align__(16) __bf16 sa[2][128 * 32];   // 2 x 8 KB
    __shared__ __align__(16) __bf16 sb[2][128 * 32];   // 2 x 8 KB

    floatx4 acc[4][4] = {};

    const int wm = (w & 1) * 64;     // wave's m-offset within tile
    const int wn = (w >> 1) * 64;    // wave's n-offset within tile

    // staging lane map: chunk = 16 rows x 32 k (1024 B); lane l -> row l/4, kelem (l&3)*8
    const int srow = l >> 2;
    const int skc  = (l & 3) * 8;

    int arow0 = m0 + w * 16 + srow;        if (arow0 > M - 1) arow0 = M - 1;
    int arow1 = m0 + (w + 4) * 16 + srow;  if (arow1 > M - 1) arow1 = M - 1;
    int brow0 = n0 + w * 16 + srow;        if (brow0 > N - 1) brow0 = N - 1;
    int brow1 = n0 + (w + 4) * 16 + srow;  if (brow1 > N - 1) brow1 = N - 1;

    const __bf16* agp0 = Ab + (long)arow0 * lda + skc;
    const __bf16* agp1 = Ab + (long)arow1 * lda + skc;
    const __bf16* bgp0 = Bb + (long)brow0 * ldb + skc;
    const __bf16* bgp1 = Bb + (long)brow1 * ldb + skc;

    auto issue = [&](int buf, int k0) {
        gload_lds16(agp0 + k0, &sa[buf][(size_t)w * 512]);
        gload_lds16(agp1 + k0, &sa[buf][(size_t)(w + 4) * 512]);
        gload_lds16(bgp0 + k0, &sb[buf][(size_t)w * 512]);
        gload_lds16(bgp1 + k0, &sb[buf][(size_t)(w + 4) * 512]);
    };

    auto compute = [&](int buf) {
        bf16x8 af[4], bfv[4];
#pragma unroll
        for (int i = 0; i < 4; ++i)
            af[i] = *reinterpret_cast<const bf16x8*>(&sa[buf][(wm + i * 16 + lr) * 32 + q * 8]);
#pragma unroll
        for (int j = 0; j < 4; ++j)
            bfv[j] = *reinterpret_cast<const bf16x8*>(&sb[buf][(wn + j * 16 + lr) * 32 + q * 8]);
#pragma unroll
        for (int i = 0; i < 4; ++i)
#pragma unroll
            for (int j = 0; j < 4; ++j)
                acc[i][j] = __builtin_amdgcn_mfma_f32_16x16x32_bf16(af[i], bfv[j], acc[i][j], 0, 0, 0);
    };

    issue(0, 0);
    __syncthreads();                       // drain prologue loads (no overlap, once)
    for (int k0 = 0; k0 < K; k0 += 64) {
        issue(1, k0 + 32);                 // in flight during compute(0)
        compute(0);
        __syncthreads();                   // all read buf0; buf1 DMA drained post-compute
        if (k0 + 64 < K) issue(0, k0 + 64);
        compute(1);
        __syncthreads();
    }

    // epilogue: D subtile (i,j): row = q*4+r, col = lr
#pragma unroll
    for (int i = 0; i < 4; ++i) {
        const int mbase = m0 + wm + i * 16 + q * 4;
#pragma unroll
        for (int j = 0; j < 4; ++j) {
            const int n = n0 + wn + j * 16 + lr;
#pragma unroll
            for (int r = 0; r < 4; ++r) {
                const int m = mbase + r;
                if (m < M && n < N) {
                    float v = acc[i][j][r];
                    if (MODE == 0) {
                        v = (v + bias[n]) * scale[n];
                        ((__bf16*)Cout)[(long)z * sCb + (long)m * ldc + n] = (__bf16)v;
                    } else if (MODE == 1) {
                        ((__bf16*)Cout)[(long)z * sCb + (long)m * ldc + n] = (__bf16)v;
                    } else { // MODE 3
                        v = v + bias[n];
                        v = v > 0.f ? v : 0.f;
                        v += addx[(long)m * ldc + n];
                        ((float*)Cout)[(long)m * ldc + n] = v;
                    }
                }
            }
        }
    }
}

// ---------------------------------------------------------------------------
// x (f32) -> xb (bf16), vectorized
// ---------------------------------------------------------------------------
__global__ __launch_bounds__(256) void convert_x(const float4* __restrict__ x4,
                                                 __bf16* __restrict__ xb, int n4)
{
    int i = blockIdx.x * 256 + threadIdx.x;
    int stride = gridDim.x * 256;
    for (; i < n4; i += stride) {
        float4 v = x4[i];
        bf16x4 o;
        o[0] = (__bf16)v.x; o[1] = (__bf16)v.y; o[2] = (__bf16)v.z; o[3] = (__bf16)v.w;
        *reinterpret_cast<bf16x4*>(xb + 4 * (long)i) = o;
    }
}

// ---------------------------------------------------------------------------
// Weights: WqkT[384][768] = [Wq|Wk]^T (bf16), WgT[768][768] = Wg^T (bf16),
// plus combined bias[384] and per-column scale[384] (1/sqrt(R) on Q cols).
// ---------------------------------------------------------------------------
__global__ __launch_bounds__(256) void prep_weights(
    const float* __restrict__ Wq, const float* __restrict__ bq,
    const float* __restrict__ Wk, const float* __restrict__ bk,
    const float* __restrict__ Wg,
    __bf16* __restrict__ WqkT, __bf16* __restrict__ WgT,
    float* __restrict__ biasqk, float* __restrict__ scaleqk)
{
    int blk = blockIdx.x, t = threadIdx.x;
    if (blk < 384) {
        int n = blk;
        const float* W = (n < RR) ? Wq : Wk;
        int nn = (n < RR) ? n : n - RR;
        for (int k = t; k < CC; k += 256)
            WqkT[(long)n * CC + k] = (__bf16)W[(long)k * RR + nn];
        if (blk == 0) {
            for (int i = t; i < 384; i += 256) {
                biasqk[i]  = (i < RR) ? bq[i] : bk[i - RR];
                scaleqk[i] = (i < RR) ? rsqrtf((float)RR) : 1.0f;
            }
        }
    } else {
        int n = blk - 384;
        for (int k = t; k < CC; k += 256)
            WgT[(long)n * CC + k] = (__bf16)Wg[(long)k * CC + n];
    }
}

// ---------------------------------------------------------------------------
// xbT[b][c][m] (m padded to 192, zeros) from xb[b][m][c]; LDS tile transpose.
// ---------------------------------------------------------------------------
__global__ __launch_bounds__(256) void transpose_x(const __bf16* __restrict__ xb,
                                                   __bf16* __restrict__ xbT)
{
    const int c0 = (blockIdx.x % 12) * 64;
    const int b  = blockIdx.x / 12;
    __shared__ __bf16 lds[64 * 194];
    const int t = threadIdx.x;

    for (int i = 0; i < 45; ++i) {
        int idx = i * 256 + t;
        int m = idx >> 6, c = idx & 63;
        lds[c * 194 + m] = xb[((long)(b * NN + m)) * CC + c0 + c];
    }
    __syncthreads();
    for (int j = 0; j < 48; ++j) {
        int idx = j * 256 + t;
        int c = idx / KPAD, m = idx % KPAD;
        __bf16 v = (m < NN) ? lds[c * 194 + m] : (__bf16)0.0f;
        xbT[((long)(b * CC + c0 + c)) * KPAD + m] = v;
    }
}

// ---------------------------------------------------------------------------
// Row softmax of S (bf16, [B][180][180]) + combine with alpha/A_phys,
// write A_comb bf16 [B][180][192] (K-padded with zeros). One wave per row.
// ---------------------------------------------------------------------------
__global__ __launch_bounds__(256) void softmax_combine(
    const __bf16* __restrict__ S, const float* __restrict__ A_phys,
    const float* __restrict__ alpha, __bf16* __restrict__ Acomb)
{
    const int w = threadIdx.x >> 6, l = threadIdx.x & 63;
    const long row = (long)blockIdx.x * 4 + w;
    const int b = (int)(row / NN), n = (int)(row % NN);
    const __bf16* Srow = S + ((long)b * NN + n) * NN;

    float v[3];
#pragma unroll
    for (int i = 0; i < 3; ++i) {
        int m = l + 64 * i;
        v[i] = (m < NN) ? (float)Srow[m] : -1e30f;
    }
    float mx = fmaxf(fmaxf(v[0], v[1]), v[2]);
    for (int off = 32; off; off >>= 1) mx = fmaxf(mx, __shfl_xor(mx, off, 64));

    float e[3], sum = 0.f;
#pragma unroll
    for (int i = 0; i < 3; ++i) {
        int m = l + 64 * i;
        e[i] = (m < NN) ? expf(v[i] - mx) : 0.f;
        sum += e[i];
    }
    for (int off = 32; off; off >>= 1) sum += __shfl_xor(sum, off, 64);

    const float a   = 1.f / (1.f + expf(-alpha[0]));
    const float inv = (1.f - a) / sum;
    __bf16* Orow = Acomb + ((long)b * NN + n) * KPAD;
#pragma unroll
    for (int i = 0; i < 3; ++i) {
        int m = l + 64 * i;
        if (m < KPAD) {
            float o = (m < NN) ? (a * A_phys[n * NN + m] + e[i] * inv) : 0.f;
            Orow[m] = (__bf16)o;
        }
    }
}

// ---------------------------------------------------------------------------
// In-place LayerNorm over channel dim; one block per row of 768.
// ---------------------------------------------------------------------------
__global__ __launch_bounds__(256) void ln_kernel(float* __restrict__ out,
                                                 const float* __restrict__ gamma,
                                                 const float* __restrict__ beta)
{
    float* p = out + (long)blockIdx.x * CC;
    const int t = threadIdx.x, w = t >> 6, l = t & 63;
    float h[3], s = 0.f, s2 = 0.f;
#pragma unroll
    for (int i = 0; i < 3; ++i) {
        h[i] = p[t + 256 * i];
        s += h[i]; s2 += h[i] * h[i];
    }
    for (int off = 32; off; off >>= 1) { s += __shfl_xor(s, off, 64); s2 += __shfl_xor(s2, off, 64); }
    __shared__ float ps[4], ps2[4];
    if (l == 0) { ps[w] = s; ps2[w] = s2; }
    __syncthreads();
    s  = ps[0] + ps[1] + ps[2] + ps[3];
    s2 = ps2[0] + ps2[1] + ps2[2] + ps2[3];
    const float mu  = s * (1.f / CC);
    const float var = s2 * (1.f / CC) - mu * mu;
    const float rs  = rsqrtf(var + 1e-5f);
#pragma unroll
    for (int i = 0; i < 3; ++i) {
        int c = t + 256 * i;
        p[c] = (h[i] - mu) * rs * gamma[c] + beta[c];
    }
}

// ---------------------------------------------------------------------------
extern "C" void kernel_launch(void* const* d_in, const int* in_sizes, int n_in,
                              void* d_out, int out_size, void* d_ws, size_t ws_size,
                              hipStream_t stream)
{
    const float* x      = (const float*)d_in[0];
    const float* Wq     = (const float*)d_in[1];
    const float* bq     = (const float*)d_in[2];
    const float* Wk     = (const float*)d_in[3];
    const float* bk     = (const float*)d_in[4];
    const float* Wg     = (const float*)d_in[5];
    const float* bg     = (const float*)d_in[6];
    const float* gamma  = (const float*)d_in[7];
    const float* beta   = (const float*)d_in[8];
    const float* alpha  = (const float*)d_in[9];
    const float* A_phys = (const float*)d_in[10];

    // ---- workspace carve (bytes). Lifetime aliases: z over xb, Acomb over QK.
    char* w = (char*)d_ws;
    __bf16* xb    = (__bf16*)(w + 0);                       // 70,778,880  (also z)
    __bf16* zbuf  = xb;
    __bf16* xbT   = (__bf16*)(w + 70778880);                // 75,497,472
    __bf16* QK    = (__bf16*)(w + 146276352);               // 35,389,440  (also Acomb)
    __bf16* Acomb = QK;
    __bf16* S     = (__bf16*)(w + 181665792);               // 16,588,800
    __bf16* WqkT  = (__bf16*)(w + 198254592);               //    589,824
    __bf16* WgT   = (__bf16*)(w + 198844416);               //  1,179,648
    float*  biasqk  = (float*)(w + 200024064);              //      1,536
    float*  scaleqk = (float*)(w + 200025600);              //      1,536

    // 1) conversions / transposes
    convert_x<<<4096, 256, 0, stream>>>((const float4*)x, xb, MROWS * CC / 4);
    prep_weights<<<384 + CC, 256, 0, stream>>>(Wq, bq, Wk, bk, Wg, WqkT, WgT, biasqk, scaleqk);
    transpose_x<<<BB * 12, 256, 0, stream>>>(xb, xbT);

    // 2) GEMM1: [46080,768] @ WqkT^T -> QK [46080,384] bf16 (Q scaled by 1/sqrt(R))
    gemm128<0><<<dim3(384 / 128, MROWS / 128, 1), 256, 0, stream>>>(
        xb, CC, 0L, WqkT, CC, 0L, QK, 384, 0L,
        MROWS, 384, CC, biasqk, scaleqk, nullptr);

    // 3) GEMM2 (batched): S[b] = Q[b] (180x192) @ K[b]^T -> [180,180] bf16
    gemm128<1><<<dim3(2, 2, BB), 256, 0, stream>>>(
        QK, 384, (long)NN * 384, QK + RR, 384, (long)NN * 384,
        S, NN, (long)NN * NN,
        NN, NN, RR, nullptr, nullptr, nullptr);

    // 4) softmax + alpha combine -> Acomb [B][180][192] bf16 (overwrites QK region)
    softmax_combine<<<MROWS / 4, 256, 0, stream>>>(S, A_phys, alpha, Acomb);

    // 5) GEMM3 (batched): z[b] = Acomb[b] (180x192) @ xbT[b]^T (192x768) -> bf16
    gemm128<1><<<dim3(CC / 128, 2, BB), 256, 0, stream>>>(
        Acomb, KPAD, (long)NN * KPAD, xbT, KPAD, (long)CC * KPAD,
        zbuf, CC, (long)NN * CC,
        NN, CC, KPAD, nullptr, nullptr, nullptr);

    // 6) GEMM4: h = x + relu(z @ Wg + bg) -> d_out f32 [46080,768]
    gemm128<3><<<dim3(CC / 128, MROWS / 128, 1), 256, 0, stream>>>(
        zbuf, CC, 0L, WgT, CC, 0L, d_out, CC, 0L,
        MROWS, CC, CC, bg, nullptr, x);

    // 7) in-place LayerNorm
    ln_kernel<<<MROWS, 256, 0, stream>>>((float*)d_out, gamma, beta);
}